// Round 1
// baseline (1172.471 us; speedup 1.0000x reference)
//
#include <hip/hip_runtime.h>
#include <hip/hip_bf16.h>
#include <math.h>

#define NTOK   4096
#define DMODEL 768
#define NHEAD  12
#define DHEAD  64
#define NLAYER 4
#define DFF    3072
#define NBLK   64
#define NEGC   -10000.0f

using frag8 = __attribute__((ext_vector_type(8))) short;   // 8 bf16
using f32x4 = __attribute__((ext_vector_type(4))) float;

typedef __attribute__((address_space(3))) void       lds_void;
typedef const __attribute__((address_space(1))) void gbl_void;

__device__ __forceinline__ void gload_lds16(const void* g, void* l) {
  __builtin_amdgcn_global_load_lds((gbl_void*)g, (lds_void*)l, 16, 0, 0);
}

// ---------------- block-wide sum over 256 threads ----------------
__device__ __forceinline__ float block_sum256(float v) {
  __shared__ float tmp[4];
  #pragma unroll
  for (int o = 32; o > 0; o >>= 1) v += __shfl_down(v, o, 64);
  __syncthreads();
  if ((threadIdx.x & 63) == 0) tmp[threadIdx.x >> 6] = v;
  __syncthreads();
  return tmp[0] + tmp[1] + tmp[2] + tmp[3];
}

// ---------------- embedding + layernorm (emit fp32 + bf16) ----------------
__global__ __launch_bounds__(256) void embed_ln_kernel(
    const int* __restrict__ ids, const float* __restrict__ emb_word,
    const float* __restrict__ emb_pos, const float* __restrict__ g,
    const float* __restrict__ b, float* __restrict__ x,
    __hip_bfloat16* __restrict__ xb)
{
  const int n = blockIdx.x;
  const int tid = threadIdx.x;
  const int id = ids[n];
  float v[3];
  #pragma unroll
  for (int j = 0; j < 3; ++j) {
    int d = tid + j * 256;
    v[j] = emb_word[(size_t)id * DMODEL + d] + emb_pos[(size_t)n * DMODEL + d];
  }
  float mu = block_sum256(v[0] + v[1] + v[2]) * (1.0f / DMODEL);
  float var = 0.f;
  #pragma unroll
  for (int j = 0; j < 3; ++j) { float t = v[j] - mu; var += t * t; }
  var = block_sum256(var) * (1.0f / DMODEL);
  float rs = rsqrtf(var + 1e-5f);
  #pragma unroll
  for (int j = 0; j < 3; ++j) {
    int d = tid + j * 256;
    float o = (v[j] - mu) * rs * g[d] + b[d];
    x[(size_t)n * DMODEL + d] = o;
    xb[(size_t)n * DMODEL + d] = (__hip_bfloat16)o;
  }
}

// ---------------- residual + Σ split-K partials + bias, then LN ----------------
__global__ __launch_bounds__(256) void add_ln_red_kernel(
    const float* __restrict__ xin, const float* __restrict__ P, size_t ps,
    int nparts, const float* __restrict__ bias2,
    const float* __restrict__ g, const float* __restrict__ b,
    float* __restrict__ dst, __hip_bfloat16* __restrict__ dstb)
{
  const int n = blockIdx.x;
  const int tid = threadIdx.x;
  float v[3];
  #pragma unroll
  for (int j = 0; j < 3; ++j) {
    int d = tid + j * 256;
    float s = xin[(size_t)n * DMODEL + d] + bias2[d];
    for (int z = 0; z < nparts; ++z)
      s += P[(size_t)z * ps + (size_t)n * DMODEL + d];
    v[j] = s;
  }
  float mu = block_sum256(v[0] + v[1] + v[2]) * (1.0f / DMODEL);
  float var = 0.f;
  #pragma unroll
  for (int j = 0; j < 3; ++j) { float t = v[j] - mu; var += t * t; }
  var = block_sum256(var) * (1.0f / DMODEL);
  float rs = rsqrtf(var + 1e-5f);
  #pragma unroll
  for (int j = 0; j < 3; ++j) {
    int d = tid + j * 256;
    float ov = (v[j] - mu) * rs * g[d] + b[d];
    dst[(size_t)n * DMODEL + d] = ov;
    dstb[(size_t)n * DMODEL + d] = (__hip_bfloat16)ov;
  }
}

// ---------------- weight convert + transpose: W(K,N) fp32 -> WT(N,K) bf16 ----------------
__global__ __launch_bounds__(256) void transpose_w_kernel(
    const float* __restrict__ W, __hip_bfloat16* __restrict__ WT, int K, int N)
{
  __shared__ float tile[32][33];
  const int n0 = blockIdx.x * 32;
  const int k0 = blockIdx.y * 32;
  const int c = threadIdx.x & 31;
  const int r0 = threadIdx.x >> 5;
  #pragma unroll
  for (int i = 0; i < 4; ++i) {
    int r = r0 + i * 8;
    tile[r][c] = W[(size_t)(k0 + r) * N + n0 + c];
  }
  __syncthreads();
  #pragma unroll
  for (int i = 0; i < 4; ++i) {
    int r = r0 + i * 8;
    WT[(size_t)(n0 + r) * K + k0 + c] = (__hip_bfloat16)tile[c][r];
  }
}

// ---------------- pack fused QKV bias (2304) ----------------
__global__ __launch_bounds__(256) void pack_bias_kernel(
    const float* __restrict__ bq, const float* __restrict__ bk,
    const float* __restrict__ bv, float* __restrict__ dst)
{
  int t = blockIdx.x * 256 + threadIdx.x;
  if (t < 3 * DMODEL)
    dst[t] = (t < DMODEL) ? bq[t] : (t < 2 * DMODEL ? bk[t - DMODEL] : bv[t - 2 * DMODEL]);
}

// ---------------- bf16 MFMA GEMM, 64x128 tile, double-buffered, optional split-K ----------------
// C = A(M x lda-rows) @ BT(N x ldb-rows)^T.  BM=64, BN=128, BK=32, 256 thr,
// 4 waves 2x2 of 32x64, 16x16x32 MFMA.  24 KB LDS -> 6 blocks/CU resident
// (latency hiding via block-level concurrency; grid is the occupancy limiter
// at these shapes).  XCD-aware bijective block swizzle for L2 panel reuse.
// blockIdx.z = K-part (offset z*Kpart, output to Cf + z*cfStride).
__global__ __launch_bounds__(256) void gemm_bf16_kernel(
    const __hip_bfloat16* __restrict__ A, int lda,
    const __hip_bfloat16* __restrict__ BT, int ldb,
    const float* __restrict__ bias,
    float* __restrict__ Cf, size_t cfStride,
    __hip_bfloat16* __restrict__ Cb,
    int Kpart, int ldC, int do_gelu)
{
  __shared__ __hip_bfloat16 Als[2][64 * 32];
  __shared__ __hip_bfloat16 Bls[2][128 * 32];
  const int tid = threadIdx.x;

  // XCD-aware bijective swizzle (8 XCDs): each XCD gets a contiguous chunk of
  // the x-fastest linearized grid -> same-XCD blocks share B-panels in L2.
  const int gx = gridDim.x;
  const int nwg = gx * gridDim.y;
  const int orig = blockIdx.y * gx + blockIdx.x;
  const int q = nwg >> 3, r = nwg & 7;
  const int xcd = orig & 7, loc = orig >> 3;
  const int wg = (xcd < r ? xcd * (q + 1) : r * (q + 1) + (xcd - r) * q) + loc;
  const int bm = (wg % gx) * 64;
  const int bn = (wg / gx) * 128;
  const int z  = blockIdx.z;
  const int koff = z * Kpart;

  const int wave = tid >> 6, lane = tid & 63;
  const int wm = (wave >> 1) * 32, wn = (wave & 1) * 64;
  const int lm = lane & 15, quad = lane >> 4;

  const int rA = wave * 16 + (lane >> 2);   // 0..63
  const int kc = (lane & 3) * 8;

  const __hip_bfloat16* Ar  = A  + (size_t)(bm + rA) * lda + koff + kc;
  const __hip_bfloat16* Br0 = BT + (size_t)(bn + rA) * ldb + koff + kc;
  const __hip_bfloat16* Br1 = BT + (size_t)(bn + 64 + rA) * ldb + koff + kc;

  f32x4 acc[2][4];
  #pragma unroll
  for (int i = 0; i < 2; ++i)
    #pragma unroll
    for (int j = 0; j < 4; ++j)
      acc[i][j] = (f32x4){0.f, 0.f, 0.f, 0.f};

  gload_lds16(Ar,  &Als[0][rA * 32 + kc]);
  gload_lds16(Br0, &Bls[0][rA * 32 + kc]);
  gload_lds16(Br1, &Bls[0][(64 + rA) * 32 + kc]);

  int p = 0;
  for (int k0 = 0; k0 < Kpart; k0 += 32, p ^= 1) {
    __syncthreads();
    const int kn = k0 + 32;
    if (kn < Kpart) {
      gload_lds16(Ar + kn,  &Als[p ^ 1][rA * 32 + kc]);
      gload_lds16(Br0 + kn, &Bls[p ^ 1][rA * 32 + kc]);
      gload_lds16(Br1 + kn, &Bls[p ^ 1][(64 + rA) * 32 + kc]);
    }
    frag8 afr[2], bfr[4];
    #pragma unroll
    for (int mt = 0; mt < 2; ++mt)
      afr[mt] = *(const frag8*)(&Als[p][(wm + mt * 16 + lm) * 32 + quad * 8]);
    #pragma unroll
    for (int nt = 0; nt < 4; ++nt)
      bfr[nt] = *(const frag8*)(&Bls[p][(wn + nt * 16 + lm) * 32 + quad * 8]);
    #pragma unroll
    for (int mt = 0; mt < 2; ++mt)
      #pragma unroll
      for (int nt = 0; nt < 4; ++nt)
        acc[mt][nt] = __builtin_amdgcn_mfma_f32_16x16x32_bf16(
            afr[mt], bfr[nt], acc[mt][nt], 0, 0, 0);
  }

  float* Cfz = Cf ? Cf + (size_t)z * cfStride : nullptr;
  #pragma unroll
  for (int mt = 0; mt < 2; ++mt)
    #pragma unroll
    for (int nt = 0; nt < 4; ++nt)
      #pragma unroll
      for (int rr = 0; rr < 4; ++rr) {
        int row = bm + wm + mt * 16 + quad * 4 + rr;
        int col = bn + wn + nt * 16 + lm;
        float v = acc[mt][nt][rr];
        if (bias) v += bias[col];
        if (do_gelu) v = 0.5f * v * (1.f + erff(v * 0.70710678118654752f));
        if (Cfz) Cfz[(size_t)row * ldC + col] = v;
        if (Cb) Cb[(size_t)row * ldC + col] = (__hip_bfloat16)v;
      }
}

// ---------------- BigBird attention: bf16 MFMA, register online-softmax ----------------
__global__ __launch_bounds__(256) void attn_kernel(
    const __hip_bfloat16* __restrict__ qkvb, const float* __restrict__ mask,
    const int* __restrict__ rand_attn, __hip_bfloat16* __restrict__ outp,
    float* __restrict__ Mpart, float* __restrict__ Lpart, float* __restrict__ Opart)
{
  const int h = blockIdx.x;
  const int item = blockIdx.y;
  const int tid = threadIdx.x;

  int qi, chunk;
  if (item < 8)       { qi = 0;        chunk = item; }
  else if (item < 70) { qi = item - 7; chunk = -1; }
  else                { qi = 63;       chunk = item - 70; }

  __shared__ __hip_bfloat16 Qs[64 * 72];
  __shared__ __hip_bfloat16 Ks[64 * 72];
  __shared__ __hip_bfloat16 VTs[64 * 72];
  __shared__ __hip_bfloat16 Ps[64 * 72];
  __shared__ int slist[8];
  __shared__ int snb;

  const __hip_bfloat16* qg = qkvb;
  const __hip_bfloat16* kg = qkvb + DMODEL;
  const __hip_bfloat16* vg = qkvb + 2 * DMODEL;
  const int ldq = 3 * DMODEL;

  const int wave = tid >> 6, lane = tid & 63;
  const int wm = wave * 16;
  const int lm = lane & 15, quad = lane >> 4;

  {
    int r = tid >> 2, c0 = (tid & 3) * 16;
    const __hip_bfloat16* qp = qg + (size_t)(qi * 64 + r) * ldq + h * 64 + c0;
    uint4 a = *(const uint4*)qp;
    uint4 b = *(const uint4*)(qp + 8);
    *(uint4*)(Qs + r * 72 + c0) = a;
    *(uint4*)(Qs + r * 72 + c0 + 8) = b;
  }
  if (tid == 0) {
    if (chunk >= 0) {
      for (int j = 0; j < 8; ++j) slist[j] = chunk * 8 + j;
      snb = 8;
    } else {
      const int* ra = rand_attn + ((size_t)h * 62 + (qi - 1)) * 3;
      if (qi == 1)       { slist[0] = 0; slist[1] = 1;  slist[2] = 2;  slist[3] = 63; }
      else if (qi == 62) { slist[0] = 0; slist[1] = 61; slist[2] = 62; slist[3] = 63; }
      else               { slist[0] = 0; slist[1] = qi - 1; slist[2] = qi; slist[3] = qi + 1; }
      slist[4] = ra[0]; slist[5] = ra[1]; slist[6] = ra[2];
      int nb = 7;
      if (qi >= 2 && qi <= 61) { slist[7] = 63; nb = 8; }
      snb = nb;
    }
  }
  __syncthreads();
  const int nb = snb;

  frag8 aq0 = *(const frag8*)(Qs + (wm + lm) * 72 + quad * 8);
  frag8 aq1 = *(const frag8*)(Qs + (wm + lm) * 72 + 32 + quad * 8);

  float mold[4], lsum[4];
  #pragma unroll
  for (int r = 0; r < 4; ++r) { mold[r] = -1e30f; lsum[r] = 0.f; }
  f32x4 oacc[4];
  #pragma unroll
  for (int t = 0; t < 4; ++t) oacc[t] = (f32x4){0.f, 0.f, 0.f, 0.f};

  const int sr = tid >> 2, sc0 = (tid & 3) * 16;

  for (int bi = 0; bi < nb; ++bi) {
    const int kb = slist[bi];
    const __hip_bfloat16* kp = kg + (size_t)(kb * 64 + sr) * ldq + h * 64 + sc0;
    const __hip_bfloat16* vp = vg + (size_t)(kb * 64 + sr) * ldq + h * 64 + sc0;
    uint4 kv0 = *(const uint4*)kp;
    uint4 kv1 = *(const uint4*)(kp + 8);
    uint4 vv0 = *(const uint4*)vp;
    uint4 vv1 = *(const uint4*)(vp + 8);
    float msk[4];
    #pragma unroll
    for (int t = 0; t < 4; ++t) msk[t] = mask[kb * 64 + t * 16 + lm];

    __syncthreads();
    *(uint4*)(Ks + sr * 72 + sc0) = kv0;
    *(uint4*)(Ks + sr * 72 + sc0 + 8) = kv1;
    {
      union { uint4 u[2]; __hip_bfloat16 h16[16]; } vu;
      vu.u[0] = vv0; vu.u[1] = vv1;
      #pragma unroll
      for (int j = 0; j < 16; ++j)
        VTs[(sc0 + j) * 72 + sr] = vu.h16[j];
    }
    __syncthreads();

    f32x4 sacc[4];
    #pragma unroll
    for (int t = 0; t < 4; ++t) sacc[t] = (f32x4){0.f, 0.f, 0.f, 0.f};
    #pragma unroll
    for (int t = 0; t < 4; ++t) {
      frag8 bk0 = *(const frag8*)(Ks + (t * 16 + lm) * 72 + quad * 8);
      frag8 bk1 = *(const frag8*)(Ks + (t * 16 + lm) * 72 + 32 + quad * 8);
      sacc[t] = __builtin_amdgcn_mfma_f32_16x16x32_bf16(aq0, bk0, sacc[t], 0, 0, 0);
      sacc[t] = __builtin_amdgcn_mfma_f32_16x16x32_bf16(aq1, bk1, sacc[t], 0, 0, 0);
    }

    float xs[4][4];
    #pragma unroll
    for (int t = 0; t < 4; ++t)
      #pragma unroll
      for (int r = 0; r < 4; ++r)
        xs[t][r] = sacc[t][r] * 0.125f + (1.f - msk[t]) * NEGC;

    float al[4], psum[4];
    #pragma unroll
    for (int r = 0; r < 4; ++r) {
      float rm = fmaxf(fmaxf(xs[0][r], xs[1][r]), fmaxf(xs[2][r], xs[3][r]));
      rm = fmaxf(rm, __shfl_xor(rm, 1, 64));
      rm = fmaxf(rm, __shfl_xor(rm, 2, 64));
      rm = fmaxf(rm, __shfl_xor(rm, 4, 64));
      rm = fmaxf(rm, __shfl_xor(rm, 8, 64));
      float mnew = fmaxf(mold[r], rm);
      al[r] = __expf(mold[r] - mnew);
      float s = 0.f;
      #pragma unroll
      for (int t = 0; t < 4; ++t) {
        float p = __expf(xs[t][r] - mnew);
        xs[t][r] = p;
        s += p;
      }
      s += __shfl_xor(s, 1, 64);
      s += __shfl_xor(s, 2, 64);
      s += __shfl_xor(s, 4, 64);
      s += __shfl_xor(s, 8, 64);
      psum[r] = s;
      mold[r] = mnew;
    }
    #pragma unroll
    for (int r = 0; r < 4; ++r) lsum[r] = lsum[r] * al[r] + psum[r];
    #pragma unroll
    for (int t = 0; t < 4; ++t)
      #pragma unroll
      for (int r = 0; r < 4; ++r)
        oacc[t][r] *= al[r];

    #pragma unroll
    for (int t = 0; t < 4; ++t)
      #pragma unroll
      for (int r = 0; r < 4; ++r)
        Ps[(wm + quad * 4 + r) * 72 + t * 16 + lm] = (__hip_bfloat16)xs[t][r];

    frag8 ap0 = *(const frag8*)(Ps + (wm + lm) * 72 + quad * 8);
    frag8 ap1 = *(const frag8*)(Ps + (wm + lm) * 72 + 32 + quad * 8);
    #pragma unroll
    for (int t = 0; t < 4; ++t) {
      frag8 bv0 = *(const frag8*)(VTs + (t * 16 + lm) * 72 + quad * 8);
      frag8 bv1 = *(const frag8*)(VTs + (t * 16 + lm) * 72 + 32 + quad * 8);
      oacc[t] = __builtin_amdgcn_mfma_f32_16x16x32_bf16(ap0, bv0, oacc[t], 0, 0, 0);
      oacc[t] = __builtin_amdgcn_mfma_f32_16x16x32_bf16(ap1, bv1, oacc[t], 0, 0, 0);
    }
  }

  if (chunk < 0) {
    #pragma unroll
    for (int r = 0; r < 4; ++r) {
      int row = qi * 64 + wm + quad * 4 + r;
      float sc2 = mask[row] / lsum[r];
      #pragma unroll
      for (int t = 0; t < 4; ++t)
        outp[(size_t)row * DMODEL + h * 64 + t * 16 + lm] =
            (__hip_bfloat16)(oacc[t][r] * sc2);
    }
  } else {
    const int idx = (h * 2 + (qi == 63 ? 1 : 0)) * 8 + chunk;
    #pragma unroll
    for (int r = 0; r < 4; ++r) {
      int row = wm + quad * 4 + r;
      #pragma unroll
      for (int t = 0; t < 4; ++t)
        Opart[(size_t)idx * 4096 + row * 64 + t * 16 + lm] = oacc[t][r];
      if (lm == 0) {
        Mpart[idx * 64 + row] = mold[r];
        Lpart[idx * 64 + row] = lsum[r];
      }
    }
  }
}

// ---------------- merge partials for global rows (qi 0 and 63) ----------------
__global__ __launch_bounds__(256) void attn_merge_kernel(
    const float* __restrict__ Mpart, const float* __restrict__ Lpart,
    const float* __restrict__ Opart, const float* __restrict__ mask,
    __hip_bfloat16* __restrict__ outp)
{
  const int h = blockIdx.x, side = blockIdx.y;
  const int qi = side ? 63 : 0;
  const int tid = threadIdx.x;
  const int r = tid >> 2;
  const int d0 = (tid & 3) * 16;
  const int base = (h * 2 + side) * 8;

  float mv[8], m = -1e30f;
  #pragma unroll
  for (int c = 0; c < 8; ++c) { mv[c] = Mpart[(base + c) * 64 + r]; m = fmaxf(m, mv[c]); }
  float sc[8], l = 0.f;
  #pragma unroll
  for (int c = 0; c < 8; ++c) {
    sc[c] = __expf(mv[c] - m);
    l += Lpart[(base + c) * 64 + r] * sc[c];
  }
  float o[16];
  #pragma unroll
  for (int d = 0; d < 16; ++d) o[d] = 0.f;
  #pragma unroll
  for (int c = 0; c < 8; ++c) {
    const float* Op = Opart + (size_t)(base + c) * 4096 + r * 64 + d0;
    #pragma unroll
    for (int d4 = 0; d4 < 4; ++d4) {
      float4 v4 = *(const float4*)(Op + d4 * 4);
      o[d4 * 4 + 0] += v4.x * sc[c];
      o[d4 * 4 + 1] += v4.y * sc[c];
      o[d4 * 4 + 2] += v4.z * sc[c];
      o[d4 * 4 + 3] += v4.w * sc[c];
    }
  }
  const int row = qi * 64 + r;
  float inv = mask[row] / l;
  #pragma unroll
  for (int d = 0; d < 16; ++d)
    outp[(size_t)row * DMODEL + h * 64 + d0 + d] = (__hip_bfloat16)(o[d] * inv);
}

// ---------------- driver ----------------
extern "C" void kernel_launch(void* const* d_in, const int* in_sizes, int n_in,
                              void* d_out, int out_size, void* d_ws, size_t ws_size,
                              hipStream_t stream)
{
  const int*   ids      = (const int*)  d_in[0];
  const float* mask     = (const float*)d_in[1];
  const int*   rand_att = (const int*)  d_in[2];
  const float* emb_word = (const float*)d_in[3];
  const float* emb_pos  = (const float*)d_in[4];
  const float* eg       = (const float*)d_in[5];
  const float* eb       = (const float*)d_in[6];
  const float* Wq = (const float*)d_in[7];
  const float* bq = (const float*)d_in[8];
  const float* Wk = (const float*)d_in[9];
  const float* bk = (const float*)d_in[10];
  const float* Wv = (const float*)d_in[11];
  const float* bv = (const float*)d_in[12];
  const float* Wo = (const float*)d_in[13];
  const float* bo = (const float*)d_in[14];
  const float* ln1g = (const float*)d_in[15];
  const float* ln1b = (const float*)d_in[16];
  const float* W1 = (const float*)d_in[17];
  const float* bf1 = (const float*)d_in[18];
  const float* W2 = (const float*)d_in[19];
  const float* bf2 = (const float*)d_in[20];
  const float* ln2g = (const float*)d_in[21];
  const float* ln2b = (const float*)d_in[22];

  const size_t ND = (size_t)NTOK * DMODEL;
  float* x   = (float*)d_ws;                               // ND f32
  __hip_bfloat16* xb = (__hip_bfloat16*)(x + ND);          // ND bf16
  float* P   = (float*)(xb + ND);                          // 3*ND f32 split-K partials
  __hip_bfloat16* qkvb = (__hip_bfloat16*)(P + 3 * ND);    // 3*ND bf16
  __hip_bfloat16* fb_b = qkvb + 3 * ND;                    // NTOK*DFF bf16
  __hip_bfloat16* ab_b = fb_b + (size_t)NTOK * DFF;        // ND bf16
  __hip_bfloat16* wqkvT = ab_b + ND;
  __hip_bfloat16* woT  = wqkvT + (size_t)3 * DMODEL * DMODEL;
  __hip_bfloat16* w1T  = woT  + (size_t)DMODEL * DMODEL;
  __hip_bfloat16* w2T  = w1T  + (size_t)DFF * DMODEL;
  float* biasf = (float*)(w2T + (size_t)DMODEL * DFF);
  float* Mpart = biasf + 3 * DMODEL;
  float* Lpart = Mpart + NHEAD * 2 * 8 * 64;
  float* Opart = Lpart + NHEAD * 2 * 8 * 64;               // 12*2*8*4096 f32

  embed_ln_kernel<<<NTOK, 256, 0, stream>>>(ids, emb_word, emb_pos, eg, eb, x, xb);

  for (int l = 0; l < NLAYER; ++l) {
    const float* Wq_l = Wq + (size_t)l * DMODEL * DMODEL;
    const float* Wk_l = Wk + (size_t)l * DMODEL * DMODEL;
    const float* Wv_l = Wv + (size_t)l * DMODEL * DMODEL;
    const float* Wo_l = Wo + (size_t)l * DMODEL * DMODEL;
    const float* W1_l = W1 + (size_t)l * DMODEL * DFF;
    const float* W2_l = W2 + (size_t)l * DFF * DMODEL;

    dim3 g32(DMODEL / 32, DMODEL / 32);
    transpose_w_kernel<<<g32, 256, 0, stream>>>(Wq_l, wqkvT, DMODEL, DMODEL);
    transpose_w_kernel<<<g32, 256, 0, stream>>>(Wk_l, wqkvT + (size_t)DMODEL * DMODEL, DMODEL, DMODEL);
    transpose_w_kernel<<<g32, 256, 0, stream>>>(Wv_l, wqkvT + (size_t)2 * DMODEL * DMODEL, DMODEL, DMODEL);
    transpose_w_kernel<<<g32, 256, 0, stream>>>(Wo_l, woT, DMODEL, DMODEL);
    transpose_w_kernel<<<dim3(DFF / 32, DMODEL / 32), 256, 0, stream>>>(W1_l, w1T, DMODEL, DFF);
    transpose_w_kernel<<<dim3(DMODEL / 32, DFF / 32), 256, 0, stream>>>(W2_l, w2T, DFF, DMODEL);
    pack_bias_kernel<<<9, 256, 0, stream>>>(bq + (size_t)l * DMODEL, bk + (size_t)l * DMODEL,
                                            bv + (size_t)l * DMODEL, biasf);

    // fused QKV (bf16 out only): 64x128 tiles -> 64 x 18 grid
    gemm_bf16_kernel<<<dim3(NTOK / 64, 3 * DMODEL / 128, 1), 256, 0, stream>>>(
        xb, DMODEL, wqkvT, DMODEL, biasf, nullptr, 0, qkvb, DMODEL, 3 * DMODEL, 0);

    attn_kernel<<<dim3(NHEAD, 78), 256, 0, stream>>>(qkvb, mask, rand_att, ab_b,
                                                     Mpart, Lpart, Opart);
    attn_merge_kernel<<<dim3(NHEAD, 2), 256, 0, stream>>>(Mpart, Lpart, Opart, mask, ab_b);

    // Wo: split-K=2 (K=768 -> 2x384), partials into P
    gemm_bf16_kernel<<<dim3(NTOK / 64, DMODEL / 128, 2), 256, 0, stream>>>(
        ab_b, DMODEL, woT, DMODEL, nullptr, P, ND, nullptr, DMODEL / 2, DMODEL, 0);
    add_ln_red_kernel<<<NTOK, 256, 0, stream>>>(x, P, ND, 2, bo + (size_t)l * DMODEL,
                                                ln1g + (size_t)l * DMODEL,
                                                ln1b + (size_t)l * DMODEL, x, xb);

    // FFN1 (gelu, bf16 out): 64 x 24 grid
    gemm_bf16_kernel<<<dim3(NTOK / 64, DFF / 128, 1), 256, 0, stream>>>(
        xb, DMODEL, w1T, DMODEL, bf1 + (size_t)l * DFF, nullptr, 0, fb_b, DMODEL, DFF, 1);

    // FFN2: split-K=3 (K=3072 -> 3x1024), partials into P
    gemm_bf16_kernel<<<dim3(NTOK / 64, DMODEL / 128, 3), 256, 0, stream>>>(
        fb_b, DFF, w2T, DFF, nullptr, P, ND, nullptr, DFF / 3, DMODEL, 0);
    add_ln_red_kernel<<<NTOK, 256, 0, stream>>>(x, P, ND, 3, bf2 + (size_t)l * DMODEL,
                                                ln2g + (size_t)l * DMODEL,
                                                ln2b + (size_t)l * DMODEL,
                                                (l == NLAYER - 1) ? (float*)d_out : x, xb);
  }
}

// Round 2
// 1084.148 us; speedup vs baseline: 1.0815x; 1.0815x over previous
//
#include <hip/hip_runtime.h>
#include <hip/hip_bf16.h>
#include <math.h>

#define NTOK   4096
#define DMODEL 768
#define NHEAD  12
#define DHEAD  64
#define NLAYER 4
#define DFF    3072
#define NBLK   64
#define NEGC   -10000.0f

using frag8 = __attribute__((ext_vector_type(8))) short;   // 8 bf16
using f32x4 = __attribute__((ext_vector_type(4))) float;

typedef __attribute__((address_space(3))) void       lds_void;
typedef const __attribute__((address_space(1))) void gbl_void;

__device__ __forceinline__ void gload_lds16(const void* g, void* l) {
  __builtin_amdgcn_global_load_lds((gbl_void*)g, (lds_void*)l, 16, 0, 0);
}

// ---------------- block-wide sum over 256 threads ----------------
__device__ __forceinline__ float block_sum256(float v) {
  __shared__ float tmp[4];
  #pragma unroll
  for (int o = 32; o > 0; o >>= 1) v += __shfl_down(v, o, 64);
  __syncthreads();
  if ((threadIdx.x & 63) == 0) tmp[threadIdx.x >> 6] = v;
  __syncthreads();
  return tmp[0] + tmp[1] + tmp[2] + tmp[3];
}

// ---------------- embedding + layernorm (emit fp32 + bf16) ----------------
__global__ __launch_bounds__(256) void embed_ln_kernel(
    const int* __restrict__ ids, const float* __restrict__ emb_word,
    const float* __restrict__ emb_pos, const float* __restrict__ g,
    const float* __restrict__ b, float* __restrict__ x,
    __hip_bfloat16* __restrict__ xb)
{
  const int n = blockIdx.x;
  const int tid = threadIdx.x;
  const int id = ids[n];
  float v[3];
  #pragma unroll
  for (int j = 0; j < 3; ++j) {
    int d = tid + j * 256;
    v[j] = emb_word[(size_t)id * DMODEL + d] + emb_pos[(size_t)n * DMODEL + d];
  }
  float mu = block_sum256(v[0] + v[1] + v[2]) * (1.0f / DMODEL);
  float var = 0.f;
  #pragma unroll
  for (int j = 0; j < 3; ++j) { float t = v[j] - mu; var += t * t; }
  var = block_sum256(var) * (1.0f / DMODEL);
  float rs = rsqrtf(var + 1e-5f);
  #pragma unroll
  for (int j = 0; j < 3; ++j) {
    int d = tid + j * 256;
    float o = (v[j] - mu) * rs * g[d] + b[d];
    x[(size_t)n * DMODEL + d] = o;
    xb[(size_t)n * DMODEL + d] = (__hip_bfloat16)o;
  }
}

// ---------------- residual + Σ split-K partials + bias, then LN ----------------
__global__ __launch_bounds__(256) void add_ln_red_kernel(
    const float* __restrict__ xin, const float* __restrict__ P, size_t ps,
    int nparts, const float* __restrict__ bias2,
    const float* __restrict__ g, const float* __restrict__ b,
    float* __restrict__ dst, __hip_bfloat16* __restrict__ dstb)
{
  const int n = blockIdx.x;
  const int tid = threadIdx.x;
  float v[3];
  #pragma unroll
  for (int j = 0; j < 3; ++j) {
    int d = tid + j * 256;
    float s = xin[(size_t)n * DMODEL + d] + bias2[d];
    for (int z = 0; z < nparts; ++z)
      s += P[(size_t)z * ps + (size_t)n * DMODEL + d];
    v[j] = s;
  }
  float mu = block_sum256(v[0] + v[1] + v[2]) * (1.0f / DMODEL);
  float var = 0.f;
  #pragma unroll
  for (int j = 0; j < 3; ++j) { float t = v[j] - mu; var += t * t; }
  var = block_sum256(var) * (1.0f / DMODEL);
  float rs = rsqrtf(var + 1e-5f);
  #pragma unroll
  for (int j = 0; j < 3; ++j) {
    int d = tid + j * 256;
    float ov = (v[j] - mu) * rs * g[d] + b[d];
    dst[(size_t)n * DMODEL + d] = ov;
    dstb[(size_t)n * DMODEL + d] = (__hip_bfloat16)ov;
  }
}

// ---------------- fused per-layer weight prep: 6 transposes + bias pack ----------------
// W(K,N) fp32 -> WT(N,K) bf16 for Wq,Wk,Wv (into wqkvT), Wo, W1, W2; pack qkv bias.
// Block map: [0,576)x4 = 768x768 mats, [2304,4608) W1 (24k x 96n tiles),
// [4608,6912) W2 (96k x 24n), [6912,6921) bias.
__global__ __launch_bounds__(256) void prep_weights_kernel(
    const float* __restrict__ Wq, const float* __restrict__ Wk,
    const float* __restrict__ Wv, const float* __restrict__ Wo,
    const float* __restrict__ W1, const float* __restrict__ W2,
    const float* __restrict__ bq, const float* __restrict__ bk,
    const float* __restrict__ bv,
    __hip_bfloat16* __restrict__ wqkvT, __hip_bfloat16* __restrict__ woT,
    __hip_bfloat16* __restrict__ w1T, __hip_bfloat16* __restrict__ w2T,
    float* __restrict__ biasf)
{
  const int id = blockIdx.x;
  if (id >= 6912) {   // bias pack (9 blocks x 256 = 2304)
    int t = (id - 6912) * 256 + threadIdx.x;
    if (t < 3 * DMODEL)
      biasf[t] = (t < DMODEL) ? bq[t] : (t < 2 * DMODEL ? bk[t - DMODEL] : bv[t - 2 * DMODEL]);
    return;
  }
  const float* src;
  __hip_bfloat16* dst;
  int K, N, local;
  if (id < 2304) {
    int m = id / 576; local = id % 576;
    src = (m == 0) ? Wq : (m == 1) ? Wk : (m == 2) ? Wv : Wo;
    dst = (m < 3) ? wqkvT + (size_t)m * DMODEL * DMODEL : woT;
    K = DMODEL; N = DMODEL;
  } else if (id < 4608) {
    local = id - 2304; src = W1; dst = w1T; K = DMODEL; N = DFF;
  } else {
    local = id - 4608; src = W2; dst = w2T; K = DFF; N = DMODEL;
  }
  const int ntiles = N / 32;
  const int n0 = (local % ntiles) * 32;
  const int k0 = (local / ntiles) * 32;

  __shared__ float tile[32][33];
  const int c = threadIdx.x & 31;
  const int r0 = threadIdx.x >> 5;
  #pragma unroll
  for (int i = 0; i < 4; ++i) {
    int r = r0 + i * 8;
    tile[r][c] = src[(size_t)(k0 + r) * N + n0 + c];
  }
  __syncthreads();
  #pragma unroll
  for (int i = 0; i < 4; ++i) {
    int r = r0 + i * 8;
    dst[(size_t)(n0 + r) * K + k0 + c] = (__hip_bfloat16)tile[c][r];
  }
}

// ---------------- bf16 MFMA GEMM, 64x128 tile, double-buffered, optional split-K ----------------
// (kept for N=768 shapes: Wo split-K=2, FFN2 split-K=3)
__global__ __launch_bounds__(256) void gemm_bf16_kernel(
    const __hip_bfloat16* __restrict__ A, int lda,
    const __hip_bfloat16* __restrict__ BT, int ldb,
    const float* __restrict__ bias,
    float* __restrict__ Cf, size_t cfStride,
    __hip_bfloat16* __restrict__ Cb,
    int Kpart, int ldC, int do_gelu)
{
  __shared__ __hip_bfloat16 Als[2][64 * 32];
  __shared__ __hip_bfloat16 Bls[2][128 * 32];
  const int tid = threadIdx.x;

  const int gx = gridDim.x;
  const int nwg = gx * gridDim.y;
  const int orig = blockIdx.y * gx + blockIdx.x;
  const int q = nwg >> 3, r = nwg & 7;
  const int xcd = orig & 7, loc = orig >> 3;
  const int wg = (xcd < r ? xcd * (q + 1) : r * (q + 1) + (xcd - r) * q) + loc;
  const int bm = (wg % gx) * 64;
  const int bn = (wg / gx) * 128;
  const int z  = blockIdx.z;
  const int koff = z * Kpart;

  const int wave = tid >> 6, lane = tid & 63;
  const int wm = (wave >> 1) * 32, wn = (wave & 1) * 64;
  const int lm = lane & 15, quad = lane >> 4;

  const int rA = wave * 16 + (lane >> 2);
  const int kc = (lane & 3) * 8;

  const __hip_bfloat16* Ar  = A  + (size_t)(bm + rA) * lda + koff + kc;
  const __hip_bfloat16* Br0 = BT + (size_t)(bn + rA) * ldb + koff + kc;
  const __hip_bfloat16* Br1 = BT + (size_t)(bn + 64 + rA) * ldb + koff + kc;

  f32x4 acc[2][4];
  #pragma unroll
  for (int i = 0; i < 2; ++i)
    #pragma unroll
    for (int j = 0; j < 4; ++j)
      acc[i][j] = (f32x4){0.f, 0.f, 0.f, 0.f};

  gload_lds16(Ar,  &Als[0][rA * 32 + kc]);
  gload_lds16(Br0, &Bls[0][rA * 32 + kc]);
  gload_lds16(Br1, &Bls[0][(64 + rA) * 32 + kc]);

  int p = 0;
  for (int k0 = 0; k0 < Kpart; k0 += 32, p ^= 1) {
    __syncthreads();
    const int kn = k0 + 32;
    if (kn < Kpart) {
      gload_lds16(Ar + kn,  &Als[p ^ 1][rA * 32 + kc]);
      gload_lds16(Br0 + kn, &Bls[p ^ 1][rA * 32 + kc]);
      gload_lds16(Br1 + kn, &Bls[p ^ 1][(64 + rA) * 32 + kc]);
    }
    frag8 afr[2], bfr[4];
    #pragma unroll
    for (int t = 0; t < 2; ++t)
      afr[t] = *(const frag8*)(&Als[p][(wm + t * 16 + lm) * 32 + quad * 8]);
    #pragma unroll
    for (int nt = 0; nt < 4; ++nt)
      bfr[nt] = *(const frag8*)(&Bls[p][(wn + nt * 16 + lm) * 32 + quad * 8]);
    #pragma unroll
    for (int mt = 0; mt < 2; ++mt)
      #pragma unroll
      for (int nt = 0; nt < 4; ++nt)
        acc[mt][nt] = __builtin_amdgcn_mfma_f32_16x16x32_bf16(
            afr[mt], bfr[nt], acc[mt][nt], 0, 0, 0);
  }

  float* Cfz = Cf ? Cf + (size_t)z * cfStride : nullptr;
  #pragma unroll
  for (int mt = 0; mt < 2; ++mt)
    #pragma unroll
    for (int nt = 0; nt < 4; ++nt)
      #pragma unroll
      for (int rr = 0; rr < 4; ++rr) {
        int row = bm + wm + mt * 16 + quad * 4 + rr;
        int col = bn + wn + nt * 16 + lm;
        float v = acc[mt][nt][rr];
        if (bias) v += bias[col];
        if (do_gelu) v = 0.5f * v * (1.f + erff(v * 0.70710678118654752f));
        if (Cfz) Cfz[(size_t)row * ldC + col] = v;
        if (Cb) Cb[(size_t)row * ldC + col] = (__hip_bfloat16)v;
      }
}

// ---------------- 256x256 8-wave 4-phase counted-vmcnt bf16 GEMM ----------------
// C = A(M x K) @ BT(N x K)^T, K = lda = ldb (row stride for both).
// BK=64, 8 waves (2M x 4N), per-wave 128x64 output, acc[8][4] f32x4.
// LDS 128 KiB: A[2][256][64] bf16 @0, B[2][256][64] bf16 @64KiB, chunk-XOR
// swizzled (chunk ^= row&7) via pre-swizzled global source (linear LDS dest,
// rule: both-sides-or-neither).  Pipeline: while computing K-tile t (buf p),
// half-tiles of t+1 are issued one-per-phase into buf p^1; gate = issue
// H1(t+2) then s_waitcnt vmcnt(2) + barrier (counted, never 0 mid-loop).
__global__ __launch_bounds__(512, 2) void gemm256_kernel(
    const __hip_bfloat16* __restrict__ A, int lda,
    const __hip_bfloat16* __restrict__ BT,
    const float* __restrict__ bias,
    __hip_bfloat16* __restrict__ Cb, int ldC,
    int K, int do_gelu)
{
  __shared__ uint4 smem4[131072 / 16];
  char* lds = (char*)smem4;
  const int tid = threadIdx.x;
  const int bm = blockIdx.x * 256;
  const int bn = blockIdx.y * 256;
  const int wave = tid >> 6, lane = tid & 63;
  const int wm = wave >> 2;            // 0..1 -> 128 output rows
  const int wn = wave & 3;             // 0..3 -> 64 output cols
  const int lm = lane & 15, quad = lane >> 4;

  // staging geometry: per phase one 16KB half-tile = 2 x gload_lds16/thread
  const int srow = tid >> 3;                 // 0..63 (row within 64-row strip)
  const int schx = ((tid & 7) ^ (srow & 7)) * 16;  // pre-swizzled byte-in-row
  const int ldst0 = tid * 16;
  const int ldst1 = 8192 + tid * 16;
  const char* Abytes = (const char*)A;
  const char* Bbytes = (const char*)BT;
  const size_t ldab = (size_t)lda * 2;

  // frag-read swizzled chunk offsets (row&7 == lm&7 for all frag rows)
  const int co0 = ((0 + quad) ^ (lm & 7)) * 16;   // k 0..31
  const int co1 = ((4 + quad) ^ (lm & 7)) * 16;   // k 32..63

  f32x4 acc[8][4];
  #pragma unroll
  for (int i = 0; i < 8; ++i)
    #pragma unroll
    for (int j = 0; j < 4; ++j)
      acc[i][j] = (f32x4){0.f, 0.f, 0.f, 0.f};

#define STAGE(BASE, ROW0, LOFF, KB) do {                                      \
    const char* _s = (BASE) + (size_t)((ROW0) + srow) * ldab + (KB) + schx;   \
    gload_lds16(_s, lds + (LOFF) + ldst0);                                    \
    gload_lds16(_s + 64 * ldab, lds + (LOFF) + ldst1);                        \
  } while (0)

  // prologue: stage K-tile 0 into buf 0 (A h0,h1, B h0,h1)
  STAGE(Abytes, bm,        0,             (size_t)0);
  STAGE(Abytes, bm + 128,  16384,         (size_t)0);
  STAGE(Bbytes, bn,        65536,         (size_t)0);
  STAGE(Bbytes, bn + 128,  65536 + 16384, (size_t)0);

  frag8 a[4][2], b[2][2];

#define RD_A(MTB) do {                                                        \
    _Pragma("unroll")                                                         \
    for (int mt = 0; mt < 4; ++mt) {                                          \
      const char* ap = Ab + (size_t)((wm * 128 + ((MTB) + mt) * 16 + lm) * 128); \
      a[mt][0] = *(const frag8*)(ap + co0);                                   \
      a[mt][1] = *(const frag8*)(ap + co1);                                   \
    } } while (0)
#define RD_B(NTB) do {                                                        \
    _Pragma("unroll")                                                         \
    for (int nt = 0; nt < 2; ++nt) {                                          \
      const char* bp = Bb + (size_t)((wn * 64 + ((NTB) + nt) * 16 + lm) * 128); \
      b[nt][0] = *(const frag8*)(bp + co0);                                   \
      b[nt][1] = *(const frag8*)(bp + co1);                                   \
    } } while (0)
#define MMQ(MTB, NTB) do {                                                    \
    _Pragma("unroll")                                                         \
    for (int mt = 0; mt < 4; ++mt)                                            \
      _Pragma("unroll")                                                       \
      for (int nt = 0; nt < 2; ++nt) {                                        \
        acc[(MTB) + mt][(NTB) + nt] = __builtin_amdgcn_mfma_f32_16x16x32_bf16( \
            a[mt][0], b[nt][0], acc[(MTB) + mt][(NTB) + nt], 0, 0, 0);        \
        acc[(MTB) + mt][(NTB) + nt] = __builtin_amdgcn_mfma_f32_16x16x32_bf16( \
            a[mt][1], b[nt][1], acc[(MTB) + mt][(NTB) + nt], 0, 0, 0);        \
      } } while (0)

  const int NT = K >> 6;
  for (int t = 0; t < NT; ++t) {
    const int p = t & 1;
    const char* Ab = lds + p * 32768;
    const char* Bb = lds + 65536 + p * 32768;
    const int qb_ = (p ^ 1) * 32768;
    const size_t kb = (size_t)(t + 1) * 128;
    const bool more = (t + 1 < NT);

    // ---- phase 1: gate on K-tile t, compute quadrant (mt0-3, nt0-1) ----
    if (more) {
      STAGE(Abytes, bm, qb_, kb);                       // H1(t+1): A half0
      asm volatile("s_waitcnt vmcnt(2)" ::: "memory");  // all of t landed
    } else {
      asm volatile("s_waitcnt vmcnt(0)" ::: "memory");
    }
    __builtin_amdgcn_sched_barrier(0);
    __builtin_amdgcn_s_barrier();
    __builtin_amdgcn_sched_barrier(0);
    RD_A(0); RD_B(0);
    __builtin_amdgcn_s_setprio(1);
    MMQ(0, 0);
    __builtin_amdgcn_s_setprio(0);
    __builtin_amdgcn_s_barrier();

    // ---- phase 2: (mt0-3, nt2-3), reuse A regs ----
    RD_B(2);
    if (more) STAGE(Abytes, bm + 128, qb_ + 16384, kb); // H2: A half1
    __builtin_amdgcn_s_barrier();
    __builtin_amdgcn_s_setprio(1);
    MMQ(0, 2);
    __builtin_amdgcn_s_setprio(0);
    __builtin_amdgcn_s_barrier();

    // ---- phase 3: (mt4-7, nt2-3), reuse B regs ----
    RD_A(4);
    if (more) STAGE(Bbytes, bn, 65536 + qb_, kb);       // H3: B half0
    __builtin_amdgcn_s_barrier();
    __builtin_amdgcn_s_setprio(1);
    MMQ(4, 2);
    __builtin_amdgcn_s_setprio(0);
    __builtin_amdgcn_s_barrier();

    // ---- phase 4: (mt4-7, nt0-1), re-read B lo ----
    RD_B(0);
    if (more) STAGE(Bbytes, bn + 128, 65536 + qb_ + 16384, kb); // H4: B half1
    __builtin_amdgcn_s_barrier();
    __builtin_amdgcn_s_setprio(1);
    MMQ(4, 0);
    __builtin_amdgcn_s_setprio(0);
    __builtin_amdgcn_s_barrier();
  }

#undef STAGE
#undef RD_A
#undef RD_B
#undef MMQ

  // ---- epilogue ----
  #pragma unroll
  for (int mt = 0; mt < 8; ++mt)
    #pragma unroll
    for (int nt = 0; nt < 4; ++nt)
      #pragma unroll
      for (int rr = 0; rr < 4; ++rr) {
        int row = bm + wm * 128 + mt * 16 + quad * 4 + rr;
        int col = bn + wn * 64 + nt * 16 + lm;
        float v = acc[mt][nt][rr] + bias[col];
        if (do_gelu) v = 0.5f * v * (1.f + erff(v * 0.70710678118654752f));
        Cb[(size_t)row * ldC + col] = (__hip_bfloat16)v;
      }
}

// ---------------- BigBird attention: bf16 MFMA, register online-softmax ----------------
__global__ __launch_bounds__(256) void attn_kernel(
    const __hip_bfloat16* __restrict__ qkvb, const float* __restrict__ mask,
    const int* __restrict__ rand_attn, __hip_bfloat16* __restrict__ outp,
    float* __restrict__ Mpart, float* __restrict__ Lpart, float* __restrict__ Opart)
{
  const int h = blockIdx.x;
  const int item = blockIdx.y;
  const int tid = threadIdx.x;

  int qi, chunk;
  if (item < 8)       { qi = 0;        chunk = item; }
  else if (item < 70) { qi = item - 7; chunk = -1; }
  else                { qi = 63;       chunk = item - 70; }

  __shared__ __hip_bfloat16 Qs[64 * 72];
  __shared__ __hip_bfloat16 Ks[64 * 72];
  __shared__ __hip_bfloat16 VTs[64 * 72];
  __shared__ __hip_bfloat16 Ps[64 * 72];
  __shared__ int slist[8];
  __shared__ int snb;

  const __hip_bfloat16* qg = qkvb;
  const __hip_bfloat16* kg = qkvb + DMODEL;
  const __hip_bfloat16* vg = qkvb + 2 * DMODEL;
  const int ldq = 3 * DMODEL;

  const int wave = tid >> 6, lane = tid & 63;
  const int wm = wave * 16;
  const int lm = lane & 15, quad = lane >> 4;

  {
    int r = tid >> 2, c0 = (tid & 3) * 16;
    const __hip_bfloat16* qp = qg + (size_t)(qi * 64 + r) * ldq + h * 64 + c0;
    uint4 a = *(const uint4*)qp;
    uint4 b = *(const uint4*)(qp + 8);
    *(uint4*)(Qs + r * 72 + c0) = a;
    *(uint4*)(Qs + r * 72 + c0 + 8) = b;
  }
  if (tid == 0) {
    if (chunk >= 0) {
      for (int j = 0; j < 8; ++j) slist[j] = chunk * 8 + j;
      snb = 8;
    } else {
      const int* ra = rand_attn + ((size_t)h * 62 + (qi - 1)) * 3;
      if (qi == 1)       { slist[0] = 0; slist[1] = 1;  slist[2] = 2;  slist[3] = 63; }
      else if (qi == 62) { slist[0] = 0; slist[1] = 61; slist[2] = 62; slist[3] = 63; }
      else               { slist[0] = 0; slist[1] = qi - 1; slist[2] = qi; slist[3] = qi + 1; }
      slist[4] = ra[0]; slist[5] = ra[1]; slist[6] = ra[2];
      int nb = 7;
      if (qi >= 2 && qi <= 61) { slist[7] = 63; nb = 8; }
      snb = nb;
    }
  }
  __syncthreads();
  const int nb = snb;

  frag8 aq0 = *(const frag8*)(Qs + (wm + lm) * 72 + quad * 8);
  frag8 aq1 = *(const frag8*)(Qs + (wm + lm) * 72 + 32 + quad * 8);

  float mold[4], lsum[4];
  #pragma unroll
  for (int r = 0; r < 4; ++r) { mold[r] = -1e30f; lsum[r] = 0.f; }
  f32x4 oacc[4];
  #pragma unroll
  for (int t = 0; t < 4; ++t) oacc[t] = (f32x4){0.f, 0.f, 0.f, 0.f};

  const int sr = tid >> 2, sc0 = (tid & 3) * 16;

  for (int bi = 0; bi < nb; ++bi) {
    const int kb = slist[bi];
    const __hip_bfloat16* kp = kg + (size_t)(kb * 64 + sr) * ldq + h * 64 + sc0;
    const __hip_bfloat16* vp = vg + (size_t)(kb * 64 + sr) * ldq + h * 64 + sc0;
    uint4 kv0 = *(const uint4*)kp;
    uint4 kv1 = *(const uint4*)(kp + 8);
    uint4 vv0 = *(const uint4*)vp;
    uint4 vv1 = *(const uint4*)(vp + 8);
    float msk[4];
    #pragma unroll
    for (int t = 0; t < 4; ++t) msk[t] = mask[kb * 64 + t * 16 + lm];

    __syncthreads();
    *(uint4*)(Ks + sr * 72 + sc0) = kv0;
    *(uint4*)(Ks + sr * 72 + sc0 + 8) = kv1;
    {
      union { uint4 u[2]; __hip_bfloat16 h16[16]; } vu;
      vu.u[0] = vv0; vu.u[1] = vv1;
      #pragma unroll
      for (int j = 0; j < 16; ++j)
        VTs[(sc0 + j) * 72 + sr] = vu.h16[j];
    }
    __syncthreads();

    f32x4 sacc[4];
    #pragma unroll
    for (int t = 0; t < 4; ++t) sacc[t] = (f32x4){0.f, 0.f, 0.f, 0.f};
    #pragma unroll
    for (int t = 0; t < 4; ++t) {
      frag8 bk0 = *(const frag8*)(Ks + (t * 16 + lm) * 72 + quad * 8);
      frag8 bk1 = *(const frag8*)(Ks + (t * 16 + lm) * 72 + 32 + quad * 8);
      sacc[t] = __builtin_amdgcn_mfma_f32_16x16x32_bf16(aq0, bk0, sacc[t], 0, 0, 0);
      sacc[t] = __builtin_amdgcn_mfma_f32_16x16x32_bf16(aq1, bk1, sacc[t], 0, 0, 0);
    }

    float xs[4][4];
    #pragma unroll
    for (int t = 0; t < 4; ++t)
      #pragma unroll
      for (int r = 0; r < 4; ++r)
        xs[t][r] = sacc[t][r] * 0.125f + (1.f - msk[t]) * NEGC;

    float al[4], psum[4];
    #pragma unroll
    for (int r = 0; r < 4; ++r) {
      float rm = fmaxf(fmaxf(xs[0][r], xs[1][r]), fmaxf(xs[2][r], xs[3][r]));
      rm = fmaxf(rm, __shfl_xor(rm, 1, 64));
      rm = fmaxf(rm, __shfl_xor(rm, 2, 64));
      rm = fmaxf(rm, __shfl_xor(rm, 4, 64));
      rm = fmaxf(rm, __shfl_xor(rm, 8, 64));
      float mnew = fmaxf(mold[r], rm);
      al[r] = __expf(mold[r] - mnew);
      float s = 0.f;
      #pragma unroll
      for (int t = 0; t < 4; ++t) {
        float p = __expf(xs[t][r] - mnew);
        xs[t][r] = p;
        s += p;
      }
      s += __shfl_xor(s, 1, 64);
      s += __shfl_xor(s, 2, 64);
      s += __shfl_xor(s, 4, 64);
      s += __shfl_xor(s, 8, 64);
      psum[r] = s;
      mold[r] = mnew;
    }
    #pragma unroll
    for (int r = 0; r < 4; ++r) lsum[r] = lsum[r] * al[r] + psum[r];
    #pragma unroll
    for (int t = 0; t < 4; ++t)
      #pragma unroll
      for (int r = 0; r < 4; ++r)
        oacc[t][r] *= al[r];

    #pragma unroll
    for (int t = 0; t < 4; ++t)
      #pragma unroll
      for (int r = 0; r < 4; ++r)
        Ps[(wm + quad * 4 + r) * 72 + t * 16 + lm] = (__hip_bfloat16)xs[t][r];

    frag8 ap0 = *(const frag8*)(Ps + (wm + lm) * 72 + quad * 8);
    frag8 ap1 = *(const frag8*)(Ps + (wm + lm) * 72 + 32 + quad * 8);
    #pragma unroll
    for (int t = 0; t < 4; ++t) {
      frag8 bv0 = *(const frag8*)(VTs + (t * 16 + lm) * 72 + quad * 8);
      frag8 bv1 = *(const frag8*)(VTs + (t * 16 + lm) * 72 + 32 + quad * 8);
      oacc[t] = __builtin_amdgcn_mfma_f32_16x16x32_bf16(ap0, bv0, oacc[t], 0, 0, 0);
      oacc[t] = __builtin_amdgcn_mfma_f32_16x16x32_bf16(ap1, bv1, oacc[t], 0, 0, 0);
    }
  }

  if (chunk < 0) {
    #pragma unroll
    for (int r = 0; r < 4; ++r) {
      int row = qi * 64 + wm + quad * 4 + r;
      float sc2 = mask[row] / lsum[r];
      #pragma unroll
      for (int t = 0; t < 4; ++t)
        outp[(size_t)row * DMODEL + h * 64 + t * 16 + lm] =
            (__hip_bfloat16)(oacc[t][r] * sc2);
    }
  } else {
    const int idx = (h * 2 + (qi == 63 ? 1 : 0)) * 8 + chunk;
    #pragma unroll
    for (int r = 0; r < 4; ++r) {
      int row = wm + quad * 4 + r;
      #pragma unroll
      for (int t = 0; t < 4; ++t)
        Opart[(size_t)idx * 4096 + row * 64 + t * 16 + lm] = oacc[t][r];
      if (lm == 0) {
        Mpart[idx * 64 + row] = mold[r];
        Lpart[idx * 64 + row] = lsum[r];
      }
    }
  }
}

// ---------------- merge partials for global rows (qi 0 and 63) ----------------
__global__ __launch_bounds__(256) void attn_merge_kernel(
    const float* __restrict__ Mpart, const float* __restrict__ Lpart,
    const float* __restrict__ Opart, const float* __restrict__ mask,
    __hip_bfloat16* __restrict__ outp)
{
  const int h = blockIdx.x, side = blockIdx.y;
  const int qi = side ? 63 : 0;
  const int tid = threadIdx.x;
  const int r = tid >> 2;
  const int d0 = (tid & 3) * 16;
  const int base = (h * 2 + side) * 8;

  float mv[8], m = -1e30f;
  #pragma unroll
  for (int c = 0; c < 8; ++c) { mv[c] = Mpart[(base + c) * 64 + r]; m = fmaxf(m, mv[c]); }
  float sc[8], l = 0.f;
  #pragma unroll
  for (int c = 0; c < 8; ++c) {
    sc[c] = __expf(mv[c] - m);
    l += Lpart[(base + c) * 64 + r] * sc[c];
  }
  float o[16];
  #pragma unroll
  for (int d = 0; d < 16; ++d) o[d] = 0.f;
  #pragma unroll
  for (int c = 0; c < 8; ++c) {
    const float* Op = Opart + (size_t)(base + c) * 4096 + r * 64 + d0;
    #pragma unroll
    for (int d4 = 0; d4 < 4; ++d4) {
      float4 v4 = *(const float4*)(Op + d4 * 4);
      o[d4 * 4 + 0] += v4.x * sc[c];
      o[d4 * 4 + 1] += v4.y * sc[c];
      o[d4 * 4 + 2] += v4.z * sc[c];
      o[d4 * 4 + 3] += v4.w * sc[c];
    }
  }
  const int row = qi * 64 + r;
  float inv = mask[row] / l;
  #pragma unroll
  for (int d = 0; d < 16; ++d)
    outp[(size_t)row * DMODEL + h * 64 + d0 + d] = (__hip_bfloat16)(o[d] * inv);
}

// ---------------- driver ----------------
extern "C" void kernel_launch(void* const* d_in, const int* in_sizes, int n_in,
                              void* d_out, int out_size, void* d_ws, size_t ws_size,
                              hipStream_t stream)
{
  const int*   ids      = (const int*)  d_in[0];
  const float* mask     = (const float*)d_in[1];
  const int*   rand_att = (const int*)  d_in[2];
  const float* emb_word = (const float*)d_in[3];
  const float* emb_pos  = (const float*)d_in[4];
  const float* eg       = (const float*)d_in[5];
  const float* eb       = (const float*)d_in[6];
  const float* Wq = (const float*)d_in[7];
  const float* bq = (const float*)d_in[8];
  const float* Wk = (const float*)d_in[9];
  const float* bk = (const float*)d_in[10];
  const float* Wv = (const float*)d_in[11];
  const float* bv = (const float*)d_in[12];
  const float* Wo = (const float*)d_in[13];
  const float* bo = (const float*)d_in[14];
  const float* ln1g = (const float*)d_in[15];
  const float* ln1b = (const float*)d_in[16];
  const float* W1 = (const float*)d_in[17];
  const float* bf1 = (const float*)d_in[18];
  const float* W2 = (const float*)d_in[19];
  const float* bf2 = (const float*)d_in[20];
  const float* ln2g = (const float*)d_in[21];
  const float* ln2b = (const float*)d_in[22];

  const size_t ND = (size_t)NTOK * DMODEL;
  float* x   = (float*)d_ws;                               // ND f32
  __hip_bfloat16* xb = (__hip_bfloat16*)(x + ND);          // ND bf16
  float* P   = (float*)(xb + ND);                          // 3*ND f32 split-K partials
  __hip_bfloat16* qkvb = (__hip_bfloat16*)(P + 3 * ND);    // 3*ND bf16
  __hip_bfloat16* fb_b = qkvb + 3 * ND;                    // NTOK*DFF bf16
  __hip_bfloat16* ab_b = fb_b + (size_t)NTOK * DFF;        // ND bf16
  __hip_bfloat16* wqkvT = ab_b + ND;
  __hip_bfloat16* woT  = wqkvT + (size_t)3 * DMODEL * DMODEL;
  __hip_bfloat16* w1T  = woT  + (size_t)DMODEL * DMODEL;
  __hip_bfloat16* w2T  = w1T  + (size_t)DFF * DMODEL;
  float* biasf = (float*)(w2T + (size_t)DMODEL * DFF);
  float* Mpart = biasf + 3 * DMODEL;
  float* Lpart = Mpart + NHEAD * 2 * 8 * 64;
  float* Opart = Lpart + NHEAD * 2 * 8 * 64;               // 12*2*8*4096 f32

  embed_ln_kernel<<<NTOK, 256, 0, stream>>>(ids, emb_word, emb_pos, eg, eb, x, xb);

  for (int l = 0; l < NLAYER; ++l) {
    const float* Wq_l = Wq + (size_t)l * DMODEL * DMODEL;
    const float* Wk_l = Wk + (size_t)l * DMODEL * DMODEL;
    const float* Wv_l = Wv + (size_t)l * DMODEL * DMODEL;
    const float* Wo_l = Wo + (size_t)l * DMODEL * DMODEL;
    const float* W1_l = W1 + (size_t)l * DMODEL * DFF;
    const float* W2_l = W2 + (size_t)l * DFF * DMODEL;

    prep_weights_kernel<<<6921, 256, 0, stream>>>(
        Wq_l, Wk_l, Wv_l, Wo_l, W1_l, W2_l,
        bq + (size_t)l * DMODEL, bk + (size_t)l * DMODEL, bv + (size_t)l * DMODEL,
        wqkvT, woT, w1T, w2T, biasf);

    // fused QKV: 256x256 8-phase kernel, grid 16x9
    gemm256_kernel<<<dim3(NTOK / 256, 3 * DMODEL / 256), 512, 0, stream>>>(
        xb, DMODEL, wqkvT, biasf, qkvb, 3 * DMODEL, DMODEL, 0);

    attn_kernel<<<dim3(NHEAD, 78), 256, 0, stream>>>(qkvb, mask, rand_att, ab_b,
                                                     Mpart, Lpart, Opart);
    attn_merge_kernel<<<dim3(NHEAD, 2), 256, 0, stream>>>(Mpart, Lpart, Opart, mask, ab_b);

    // Wo: split-K=2 (K=768 -> 2x384), partials into P
    gemm_bf16_kernel<<<dim3(NTOK / 64, DMODEL / 128, 2), 256, 0, stream>>>(
        ab_b, DMODEL, woT, DMODEL, nullptr, P, ND, nullptr, DMODEL / 2, DMODEL, 0);
    add_ln_red_kernel<<<NTOK, 256, 0, stream>>>(x, P, ND, 2, bo + (size_t)l * DMODEL,
                                                ln1g + (size_t)l * DMODEL,
                                                ln1b + (size_t)l * DMODEL, x, xb);

    // FFN1 (gelu): 256x256 8-phase kernel, grid 16x12
    gemm256_kernel<<<dim3(NTOK / 256, DFF / 256), 512, 0, stream>>>(
        xb, DMODEL, w1T, bf1 + (size_t)l * DFF, fb_b, DFF, DMODEL, 1);

    // FFN2: split-K=3 (K=3072 -> 3x1024), partials into P
    gemm_bf16_kernel<<<dim3(NTOK / 64, DMODEL / 128, 3), 256, 0, stream>>>(
        fb_b, DFF, w2T, DFF, nullptr, P, ND, nullptr, DFF / 3, DMODEL, 0);
    add_ln_red_kernel<<<NTOK, 256, 0, stream>>>(x, P, ND, 3, bf2 + (size_t)l * DMODEL,
                                                ln2g + (size_t)l * DMODEL,
                                                ln2b + (size_t)l * DMODEL,
                                                (l == NLAYER - 1) ? (float*)d_out : x, xb);
  }
}